// Round 2
// baseline (194.584 us; speedup 1.0000x reference)
//
#include <hip/hip_runtime.h>
#include <math.h>

// out[i] = sigmoid( X[i,:] . wcomp + c )  where
//   wcomp = W1@W2@W3@W4@W5  (7-vector),  c = ((((b1@W2+b2)@W3+b3)@W4+b4)@W5+b5)
// Streaming kernel: 112 MB read + 16 MB write, memory-bound.
// v2: LDS staging so every global load instruction is lane-stride-1
// (previous version strided 112 B per lane within one instruction -> TA/L1
//  request inflation throttled achieved BW).

__global__ __launch_bounds__(256) void SimpleNN2_kernel(
    const float* __restrict__ X,
    const float* __restrict__ W1, const float* __restrict__ b1,
    const float* __restrict__ W2, const float* __restrict__ b2,
    const float* __restrict__ W3, const float* __restrict__ b3,
    const float* __restrict__ W4, const float* __restrict__ b4,
    const float* __restrict__ W5, const float* __restrict__ b5,
    float* __restrict__ out, int nrows)
{
    __shared__ float lds[7168];   // 1024 rows * 7 floats = 28 KiB
    __shared__ float sw[8];       // sw[0..6] composed weight, sw[7] composed bias

    const int t = threadIdx.x;

    if (t == 0) {
        // Compose the 7->5->4->3->2->1 chain (~300 FLOPs, L2-cached reads).
        float A[7][5], B[7][4], C[7][3], D[7][2];
        for (int i = 0; i < 7; ++i)
            for (int j = 0; j < 5; ++j) A[i][j] = W1[i * 5 + j];
        for (int i = 0; i < 7; ++i)
            for (int j = 0; j < 4; ++j) {
                float s = 0.f;
                for (int k = 0; k < 5; ++k) s += A[i][k] * W2[k * 4 + j];
                B[i][j] = s;
            }
        for (int i = 0; i < 7; ++i)
            for (int j = 0; j < 3; ++j) {
                float s = 0.f;
                for (int k = 0; k < 4; ++k) s += B[i][k] * W3[k * 3 + j];
                C[i][j] = s;
            }
        for (int i = 0; i < 7; ++i)
            for (int j = 0; j < 2; ++j) {
                float s = 0.f;
                for (int k = 0; k < 3; ++k) s += C[i][k] * W4[k * 2 + j];
                D[i][j] = s;
            }
        for (int i = 0; i < 7; ++i)
            sw[i] = D[i][0] * W5[0] + D[i][1] * W5[1];

        float v2[4], v3[3], v4[2];
        for (int j = 0; j < 4; ++j) {
            float s = b2[j];
            for (int k = 0; k < 5; ++k) s += b1[k] * W2[k * 4 + j];
            v2[j] = s;
        }
        for (int j = 0; j < 3; ++j) {
            float s = b3[j];
            for (int k = 0; k < 4; ++k) s += v2[k] * W3[k * 3 + j];
            v3[j] = s;
        }
        for (int j = 0; j < 2; ++j) {
            float s = b4[j];
            for (int k = 0; k < 3; ++k) s += v3[k] * W4[k * 2 + j];
            v4[j] = s;
        }
        sw[7] = v4[0] * W5[0] + v4[1] * W5[1] + b5[0];
    }

    // ---- Stage 1024 rows (1792 float4) into LDS, lane-stride-1 coalesced ----
    const float4* __restrict__ X4 = reinterpret_cast<const float4*>(X);
    float4* lds4 = reinterpret_cast<float4*>(lds);
    const int nf4 = (nrows * 7) >> 2;             // total float4 count (28M for 4M rows)
    const int base = blockIdx.x * 1792;

    #pragma unroll
    for (int k = 0; k < 7; ++k) {
        int idx = base + t + 256 * k;
        if (idx < nf4) lds4[t + 256 * k] = X4[idx];
    }
    __syncthreads();

    const float w0 = sw[0], w1 = sw[1], w2 = sw[2], w3 = sw[3];
    const float w4 = sw[4], w5 = sw[5], w6 = sw[6], c = sw[7];

    // ---- Each thread: 4 rows = 28 floats from LDS, one float4 store ----
    const int ngroups = nrows >> 2;
    const int g = blockIdx.x * 256 + t;
    if (g < ngroups) {
        const float4* my = reinterpret_cast<const float4*>(lds) + t * 7;
        float a[28];
        #pragma unroll
        for (int k = 0; k < 7; ++k) {
            float4 f = my[k];
            a[4 * k + 0] = f.x;
            a[4 * k + 1] = f.y;
            a[4 * k + 2] = f.z;
            a[4 * k + 3] = f.w;
        }
        float4 r;
        float* rp = &r.x;
        #pragma unroll
        for (int rr = 0; rr < 4; ++rr) {
            const float* row = &a[rr * 7];
            float s = c + row[0] * w0 + row[1] * w1 + row[2] * w2 + row[3] * w3
                        + row[4] * w4 + row[5] * w5 + row[6] * w6;
            rp[rr] = 1.0f / (1.0f + __expf(-s));
        }
        reinterpret_cast<float4*>(out)[g] = r;
    }

    // Tail rows (nrows % 4) — unused for 4M rows, kept for generality.
    if (blockIdx.x == 0 && t < (nrows & 3)) {
        int r = ((nrows >> 2) << 2) + t;
        const float* row = X + (size_t)r * 7;
        float s = c;
        #pragma unroll
        for (int j = 0; j < 7; ++j) s += row[j] * sw[j];
        out[r] = 1.0f / (1.0f + __expf(-s));
    }
}

extern "C" void kernel_launch(void* const* d_in, const int* in_sizes, int n_in,
                              void* d_out, int out_size, void* d_ws, size_t ws_size,
                              hipStream_t stream) {
    const float* X  = (const float*)d_in[0];
    const float* W1 = (const float*)d_in[1];
    const float* b1 = (const float*)d_in[2];
    const float* W2 = (const float*)d_in[3];
    const float* b2 = (const float*)d_in[4];
    const float* W3 = (const float*)d_in[5];
    const float* b3 = (const float*)d_in[6];
    const float* W4 = (const float*)d_in[7];
    const float* b4 = (const float*)d_in[8];
    const float* W5 = (const float*)d_in[9];
    const float* b5 = (const float*)d_in[10];
    float* out = (float*)d_out;

    const int nrows = in_sizes[0] / 7;     // 4,000,000
    const int ngroups = nrows >> 2;        // 1,000,000 groups of 4 rows
    int blocks = (ngroups + 255) / 256;    // 3907
    if (blocks < 1) blocks = 1;

    SimpleNN2_kernel<<<blocks, 256, 0, stream>>>(
        X, W1, b1, W2, b2, W3, b3, W4, b4, W5, b5, out, nrows);
}

// Round 4
// 191.906 us; speedup vs baseline: 1.0140x; 1.0140x over previous
//
#include <hip/hip_runtime.h>
#include <math.h>

// out[i] = sigmoid( X[i,:] . wcomp + c )  where
//   wcomp = W1@W2@W3@W4@W5  (7-vector),  c = ((((b1@W2+b2)@W3+b3)@W4+b4)@W5+b5)
// v3: two kernels. Kernel A (1 wave) composes the 8 coefficients into d_ws.
// Kernel B is a pure stream: LDS-staged coalesced loads, zero divergence,
// uniform scalar loads of the coefficients. 112 MB read + 16 MB write.

__global__ void nn_compose(
    const float* __restrict__ W1, const float* __restrict__ b1,
    const float* __restrict__ W2, const float* __restrict__ b2,
    const float* __restrict__ W3, const float* __restrict__ b3,
    const float* __restrict__ W4, const float* __restrict__ b4,
    const float* __restrict__ W5, const float* __restrict__ b5,
    float* __restrict__ wout)
{
    if (threadIdx.x != 0) return;
    float A[7][5], B[7][4], C[7][3], D[7][2];
    for (int i = 0; i < 7; ++i)
        for (int j = 0; j < 5; ++j) A[i][j] = W1[i * 5 + j];
    for (int i = 0; i < 7; ++i)
        for (int j = 0; j < 4; ++j) {
            float s = 0.f;
            for (int k = 0; k < 5; ++k) s += A[i][k] * W2[k * 4 + j];
            B[i][j] = s;
        }
    for (int i = 0; i < 7; ++i)
        for (int j = 0; j < 3; ++j) {
            float s = 0.f;
            for (int k = 0; k < 4; ++k) s += B[i][k] * W3[k * 3 + j];
            C[i][j] = s;
        }
    for (int i = 0; i < 7; ++i)
        for (int j = 0; j < 2; ++j) {
            float s = 0.f;
            for (int k = 0; k < 3; ++k) s += C[i][k] * W4[k * 2 + j];
            D[i][j] = s;
        }
    for (int i = 0; i < 7; ++i)
        wout[i] = D[i][0] * W5[0] + D[i][1] * W5[1];

    float v2[4], v3[3], v4[2];
    for (int j = 0; j < 4; ++j) {
        float s = b2[j];
        for (int k = 0; k < 5; ++k) s += b1[k] * W2[k * 4 + j];
        v2[j] = s;
    }
    for (int j = 0; j < 3; ++j) {
        float s = b3[j];
        for (int k = 0; k < 4; ++k) s += v2[k] * W3[k * 3 + j];
        v3[j] = s;
    }
    for (int j = 0; j < 2; ++j) {
        float s = b4[j];
        for (int k = 0; k < 3; ++k) s += v3[k] * W4[k * 2 + j];
        v4[j] = s;
    }
    wout[7] = v4[0] * W5[0] + v4[1] * W5[1] + b5[0];
}

__global__ __launch_bounds__(256) void nn_main(
    const float4* __restrict__ X4,
    const float* __restrict__ w,   // 8 composed coefficients (in d_ws)
    float4* __restrict__ out4,
    float* __restrict__ out,
    const float* __restrict__ X,
    int nrows)
{
    __shared__ float4 lds4[1792];  // 1024 rows * 7 floats = 28 KiB

    // Uniform (scalar) loads of the composed coefficients.
    const float w0 = w[0], w1 = w[1], w2 = w[2], w3 = w[3];
    const float w4 = w[4], w5 = w[5], w6 = w[6], c = w[7];

    const int t = threadIdx.x;
    const int nf4 = (nrows * 7) >> 2;       // 7M float4 for 4M rows
    const int base = blockIdx.x * 1792;

    // Stage 1792 contiguous float4 (1024 rows), lane-stride-1 coalesced.
    #pragma unroll
    for (int k = 0; k < 7; ++k) {
        int idx = base + t + 256 * k;
        if (idx < nf4) lds4[t + 256 * k] = X4[idx];
    }
    __syncthreads();

    // Each thread: 4 rows = 7 float4 from LDS (bank-balanced: class (7t+k)%8
    // covers all 8 bank-quads exactly 8x/wave), one coalesced float4 store.
    const int ngroups = nrows >> 2;
    const int g = blockIdx.x * 256 + t;
    if (g < ngroups) {
        const float4* my = lds4 + t * 7;
        float a[28];
        #pragma unroll
        for (int k = 0; k < 7; ++k) {
            float4 f = my[k];
            a[4 * k + 0] = f.x;
            a[4 * k + 1] = f.y;
            a[4 * k + 2] = f.z;
            a[4 * k + 3] = f.w;
        }
        float4 r;
        float* rp = &r.x;
        #pragma unroll
        for (int rr = 0; rr < 4; ++rr) {
            const float* row = &a[rr * 7];
            float s = c + row[0] * w0 + row[1] * w1 + row[2] * w2 + row[3] * w3
                        + row[4] * w4 + row[5] * w5 + row[6] * w6;
            rp[rr] = 1.0f / (1.0f + __expf(-s));
        }
        out4[g] = r;
    }

    // Tail rows (nrows % 4) — zero for 4M rows, kept for generality.
    if (blockIdx.x == 0 && t < (nrows & 3)) {
        int r = ((nrows >> 2) << 2) + t;
        const float* row = X + (size_t)r * 7;
        float s = c;
        #pragma unroll
        for (int j = 0; j < 7; ++j) {
            float wj = (j == 0) ? w0 : (j == 1) ? w1 : (j == 2) ? w2 :
                       (j == 3) ? w3 : (j == 4) ? w4 : (j == 5) ? w5 : w6;
            s += row[j] * wj;
        }
        out[r] = 1.0f / (1.0f + __expf(-s));
    }
}

extern "C" void kernel_launch(void* const* d_in, const int* in_sizes, int n_in,
                              void* d_out, int out_size, void* d_ws, size_t ws_size,
                              hipStream_t stream) {
    const float* X  = (const float*)d_in[0];
    const float* W1 = (const float*)d_in[1];
    const float* b1 = (const float*)d_in[2];
    const float* W2 = (const float*)d_in[3];
    const float* b2 = (const float*)d_in[4];
    const float* W3 = (const float*)d_in[5];
    const float* b3 = (const float*)d_in[6];
    const float* W4 = (const float*)d_in[7];
    const float* b4 = (const float*)d_in[8];
    const float* W5 = (const float*)d_in[9];
    const float* b5 = (const float*)d_in[10];
    float* out = (float*)d_out;
    float* wcomp = (float*)d_ws;           // 8 floats of scratch

    const int nrows = in_sizes[0] / 7;     // 4,000,000
    const int ngroups = nrows >> 2;        // 1,000,000 groups of 4 rows
    int blocks = (ngroups + 255) / 256;    // 3907
    if (blocks < 1) blocks = 1;

    nn_compose<<<1, 64, 0, stream>>>(W1, b1, W2, b2, W3, b3, W4, b4, W5, b5, wcomp);
    nn_main<<<blocks, 256, 0, stream>>>(
        reinterpret_cast<const float4*>(X), wcomp,
        reinterpret_cast<float4*>(out), out, X, nrows);
}